// Round 3
// baseline (180.351 us; speedup 1.0000x reference)
//
#include <hip/hip_runtime.h>
#include <hip/hip_bf16.h>
#include <stdint.h>

// LNLinearSigmoid: LayerNorm(x) @ W^T -> sigmoid
// x: [16384][2048] f32, W: [2048][2048] f32 -> out [16384][2048] f32
// Round 3: 256x256 tile, 8-phase schedule with ONE barrier per phase
// (shifted stage map keeps every restage >=2 phases after last read),
// 32x32x16 bf16 MFMA (2382 TF ceiling), counted vmcnt(6), setprio,
// XCD swizzle, T2 LDS XOR swizzle. LN+wconv merged into one dispatch.
// ws >= 75.5 MB.

typedef __attribute__((ext_vector_type(4))) float f32x4;
typedef __attribute__((ext_vector_type(16))) float f32x16;
typedef __attribute__((ext_vector_type(8))) __bf16 b16x8;

__device__ __forceinline__ void async16(void* lds_p, const void* g) {
  __builtin_amdgcn_global_load_lds(
      (const __attribute__((address_space(1))) void*)g,
      (__attribute__((address_space(3))) void*)lds_p, 16, 0, 0);
}

__device__ __forceinline__ unsigned short f2bf(float f) {
  uint32_t u = __float_as_uint(f);
  u += 0x7FFFu + ((u >> 16) & 1u);
  return (unsigned short)(u >> 16);
}

// ---------------- LN (blocks 0..16383) + W conv (blocks 16384..20479) ------
__global__ __launch_bounds__(256) void ln_wconv_kernel(
    const float* __restrict__ x, unsigned short* __restrict__ xn,
    const float* __restrict__ W, unsigned short* __restrict__ Wb) {
  const int t = threadIdx.x;
  if (blockIdx.x >= 16384) {
    const size_t i = (size_t)(blockIdx.x - 16384) * 256 + t;
    float4 v = ((const float4*)W)[i];
    ushort4 o;
    o.x = f2bf(v.x); o.y = f2bf(v.y); o.z = f2bf(v.z); o.w = f2bf(v.w);
    ((ushort4*)Wb)[i] = o;
    return;
  }
  const int row = blockIdx.x;
  const float4* xr = (const float4*)(x + (size_t)row * 2048);
  float4 a = xr[t];
  float4 b = xr[t + 256];
  float s = a.x + a.y + a.z + a.w + b.x + b.y + b.z + b.w;
  float q = a.x * a.x + a.y * a.y + a.z * a.z + a.w * a.w +
            b.x * b.x + b.y * b.y + b.z * b.z + b.w * b.w;
#pragma unroll
  for (int off = 32; off > 0; off >>= 1) {
    s += __shfl_down(s, off);
    q += __shfl_down(q, off);
  }
  __shared__ float red[8];
  const int w = t >> 6;
  if ((t & 63) == 0) { red[w] = s; red[4 + w] = q; }
  __syncthreads();
  s = red[0] + red[1] + red[2] + red[3];
  q = red[4] + red[5] + red[6] + red[7];
  const float mean = s * (1.0f / 2048.0f);
  const float var = fmaxf(q * (1.0f / 2048.0f) - mean * mean, 0.0f);
  const float scl = rsqrtf(var + 1e-5f);
  ushort4 o0, o1;
  o0.x = f2bf((a.x - mean) * scl);
  o0.y = f2bf((a.y - mean) * scl);
  o0.z = f2bf((a.z - mean) * scl);
  o0.w = f2bf((a.w - mean) * scl);
  o1.x = f2bf((b.x - mean) * scl);
  o1.y = f2bf((b.y - mean) * scl);
  o1.z = f2bf((b.z - mean) * scl);
  o1.w = f2bf((b.w - mean) * scl);
  ushort4* orow = (ushort4*)(xn + (size_t)row * 2048);
  orow[t] = o0;
  orow[t + 256] = o1;
}

// ---------------- 256x256 8-phase GEMM, 32x32x16, 1 barrier/phase ---------
// LDS: buf*65536 + {A0:0, A1:16K, B0:32K, B1:48K}, region = 128 rows x 128B.
// Wave (8 = 2Mx4N): rows = qm*128 + wr*64 + mi*32 + (l&31)
//                   cols = qn*128 + wc*32 + (l&31)
// Phases/K-tile-pair: Q(0,0),(0,1),(1,1),(1,0) on buf0 then buf1; each phase
// newly reads ONE half-tile. Stage map (>=2 phases after region's last read):
// P1:A1(t1)  P3:B0,A0(t2)  P4:B1(t2)  P5:A1(t2)  P7:B0,A0(t3)  P8:B1(t3).
// vmcnt(6) at P4/P8 (ledger-verified). One s_barrier per phase.

#define STG_A(buf, h, kt)                                              \
  do {                                                                 \
    const char* s_ = pA + (size_t)((h) * 128) * 4096 + (kt) * 128;     \
    char* d_ = lds + (buf) * 65536 + (h) * 16384 + tid * 16;           \
    async16(d_, s_);                                                   \
    async16(d_ + 8192, s_ + 64 * 4096);                                \
  } while (0)

#define STG_B(buf, h, kt)                                              \
  do {                                                                 \
    const char* s_ = pB + (size_t)((h) * 128) * 4096 + (kt) * 128;     \
    char* d_ = lds + 32768 + (buf) * 65536 + (h) * 16384 + tid * 16;   \
    async16(d_, s_);                                                   \
    async16(d_ + 8192, s_ + 64 * 4096);                                \
  } while (0)

#define LDA(buf, qm)                                                   \
  do {                                                                 \
    const char* base_ = lds + (buf) * 65536 + (qm) * 16384 + rowA;     \
    _Pragma("unroll") for (int mi_ = 0; mi_ < 2; ++mi_) {              \
      _Pragma("unroll") for (int s_ = 0; s_ < 4; ++s_) {               \
        aF[mi_][s_] = *(const b16x8*)(base_ + mi_ * 4096 + ofs[s_]);   \
      }                                                                \
    }                                                                  \
  } while (0)

#define LDB(dstf, buf, qn)                                             \
  do {                                                                 \
    const char* base_ = lds + (buf) * 65536 + 32768 + (qn) * 16384 + rowB; \
    _Pragma("unroll") for (int s_ = 0; s_ < 4; ++s_) {                 \
      dstf[s_] = *(const b16x8*)(base_ + ofs[s_]);                     \
    }                                                                  \
  } while (0)

#define MFMA_Q(qm, qn, BF)                                             \
  do {                                                                 \
    __builtin_amdgcn_s_setprio(1);                                     \
    _Pragma("unroll") for (int s_ = 0; s_ < 4; ++s_) {                 \
      _Pragma("unroll") for (int mi_ = 0; mi_ < 2; ++mi_) {            \
        acc[(qm) * 2 + mi_][qn] = __builtin_amdgcn_mfma_f32_32x32x16_bf16( \
            aF[mi_][s_], BF[s_], acc[(qm) * 2 + mi_][qn], 0, 0, 0);    \
      }                                                                \
    }                                                                  \
    __builtin_amdgcn_s_setprio(0);                                     \
  } while (0)

#define BARR                                                           \
  do {                                                                 \
    __builtin_amdgcn_s_barrier();                                      \
    asm volatile("" ::: "memory");                                     \
  } while (0)

#define LGKM0                                                          \
  do {                                                                 \
    asm volatile("s_waitcnt lgkmcnt(0)" ::: "memory");                 \
    __builtin_amdgcn_sched_barrier(0);                                 \
  } while (0)

#define VMC(n) asm volatile("s_waitcnt vmcnt(" #n ")" ::: "memory")

__global__ __launch_bounds__(512, 2) void gemm8p(
    const unsigned short* __restrict__ A, const unsigned short* __restrict__ B,
    float* __restrict__ C) {
  __shared__ __align__(16) char lds[131072];

  const int bid0 = blockIdx.x;                       // 512 blocks
  const int bid = (bid0 & 7) * 64 + (bid0 >> 3);     // XCD swizzle (512%8==0)
  const int bm = bid >> 3;                           // 0..63
  const int bn = bid & 7;                            // 0..7

  const int tid = threadIdx.x;
  const int w = tid >> 6, l = tid & 63;
  const int wr = w >> 2, wc = w & 3;
  const int l31 = l & 31;
  const int h16 = (l >> 5) * 16;
  const int sw7 = (l & 7) << 4;

  // staging source (linear LDS dest, inverse-swizzled global source)
  const int arow = tid >> 3;
  const int swz = ((tid & 7) << 4) ^ ((arow & 7) << 4);
  const char* pA = (const char*)A + (size_t)(bm * 256 + arow) * 4096 + swz;
  const char* pB = (const char*)B + (size_t)(bn * 256 + arow) * 4096 + swz;

  // swizzled ds_read k-offsets for ksteps 0..3
  int ofs[4];
#pragma unroll
  for (int s = 0; s < 4; ++s) ofs[s] = (s * 32 + h16) ^ sw7;
  const int rowA = (wr * 64 + l31) * 128;
  const int rowB = (wc * 32 + l31) * 128;

  f32x16 acc[4][2] = {};   // [qm*2+mi][qn]
  b16x8 aF[2][4], bF0[4], bF1[4];

  // prologue: t0 full (A0,B0,B1,A1), then t1: B0,A0 then B1  (14 loads)
  STG_A(0, 0, 0); STG_B(0, 0, 0); STG_B(0, 1, 0); STG_A(0, 1, 0);
  STG_B(1, 0, 1); STG_A(1, 0, 1); STG_B(1, 1, 1);
  VMC(6);
  BARR;

#pragma unroll 1
  for (int it = 0; it < 16; ++it) {
    const int t1 = 2 * it + 1, t2 = 2 * it + 2, t3 = 2 * it + 3;
    const bool s2 = (it < 15);   // t2,t3 valid iff it<15

    // P1: Q(0,0) buf0
    STG_A(1, 1, t1);
    LDA(0, 0); LDB(bF0, 0, 0);
    BARR; LGKM0; MFMA_Q(0, 0, bF0);

    // P2: Q(0,1) buf0
    LDB(bF1, 0, 1);
    BARR; LGKM0; MFMA_Q(0, 1, bF1);

    // P3: Q(1,1) buf0
    if (s2) { STG_B(0, 0, t2); STG_A(0, 0, t2); }
    LDA(0, 1);
    BARR; LGKM0; MFMA_Q(1, 1, bF1);

    // P4: Q(1,0) buf0
    if (s2) STG_B(0, 1, t2);
    BARR; MFMA_Q(1, 0, bF0);
    if (s2) { VMC(6); } else { VMC(0); }

    // P5: Q(0,0) buf1
    if (s2) STG_A(0, 1, t2);
    LDA(1, 0); LDB(bF0, 1, 0);
    BARR; LGKM0; MFMA_Q(0, 0, bF0);

    // P6: Q(0,1) buf1
    LDB(bF1, 1, 1);
    BARR; LGKM0; MFMA_Q(0, 1, bF1);

    // P7: Q(1,1) buf1
    if (s2) { STG_B(1, 0, t3); STG_A(1, 0, t3); }
    LDA(1, 1);
    BARR; LGKM0; MFMA_Q(1, 1, bF1);

    // P8: Q(1,0) buf1
    if (s2) STG_B(1, 1, t3);
    BARR; MFMA_Q(1, 0, bF0);
    if (s2) VMC(6);
  }

  // epilogue: sigmoid + store.
  // 32x32 C/D layout: col = lane&31, row = (reg&3) + 8*(reg>>2) + 4*(lane>>5)
  float* gC = C + (size_t)(bm * 256) * 2048 + bn * 256;
  const int rbase = 4 * (l >> 5);
#pragma unroll
  for (int qm = 0; qm < 2; ++qm) {
#pragma unroll
    for (int mi = 0; mi < 2; ++mi) {
#pragma unroll
      for (int qn = 0; qn < 2; ++qn) {
        const f32x16 v = acc[qm * 2 + mi][qn];
        const int col = qn * 128 + wc * 32 + l31;
        const int row0 = qm * 128 + wr * 64 + mi * 32 + rbase;
#pragma unroll
        for (int r = 0; r < 16; ++r) {
          const int row = row0 + (r & 3) + 8 * (r >> 2);
          const float y = v[r];
          gC[(size_t)row * 2048 + col] = 1.0f / (1.0f + __expf(-y));
        }
      }
    }
  }
}

extern "C" void kernel_launch(void* const* d_in, const int* in_sizes, int n_in,
                              void* d_out, int out_size, void* d_ws, size_t ws_size,
                              hipStream_t stream) {
  const float* x = (const float*)d_in[0];
  const float* W = (const float*)d_in[1];
  float* out = (float*)d_out;

  unsigned short* xnb = (unsigned short*)d_ws;
  unsigned short* Wb =
      (unsigned short*)((char*)d_ws + (size_t)16384 * 2048 * 2);

  ln_wconv_kernel<<<16384 + 4096, 256, 0, stream>>>(x, xnb, W, Wb);
  gemm8p<<<512, 512, 0, stream>>>(xnb, Wb, out);
}

// Round 4
// 164.635 us; speedup vs baseline: 1.0955x; 1.0955x over previous
//
#include <hip/hip_runtime.h>
#include <hip/hip_bf16.h>
#include <stdint.h>

// LNLinearSigmoid: LayerNorm(x) @ W^T -> sigmoid
// Round 4: round-2 GEMM base (256x256, 8 phases, 2 barriers/phase, 16x16x32
// MFMA, zero-conflict XOR swizzle, vmcnt(6)) + register-prefetch interleave:
// every phase's ds_reads issue inside the PREVIOUS phase's MFMA cluster
// (WAR reuse of fragment regs; no VGPR growth). ws >= 75.5 MB.

typedef __attribute__((ext_vector_type(4))) float f32x4;
typedef __attribute__((ext_vector_type(8))) __bf16 b16x8;

__device__ __forceinline__ void async16(void* lds_p, const void* g) {
  __builtin_amdgcn_global_load_lds(
      (const __attribute__((address_space(1))) void*)g,
      (__attribute__((address_space(3))) void*)lds_p, 16, 0, 0);
}

__device__ __forceinline__ unsigned short f2bf(float f) {
  uint32_t u = __float_as_uint(f);
  u += 0x7FFFu + ((u >> 16) & 1u);
  return (unsigned short)(u >> 16);
}

// ---------------- LN (blocks 0..16383) + W conv (blocks 16384..20479) ------
__global__ __launch_bounds__(256) void ln_wconv_kernel(
    const float* __restrict__ x, unsigned short* __restrict__ xn,
    const float* __restrict__ W, unsigned short* __restrict__ Wb) {
  const int t = threadIdx.x;
  if (blockIdx.x >= 16384) {
    const size_t i = (size_t)(blockIdx.x - 16384) * 256 + t;
    float4 v = ((const float4*)W)[i];
    ushort4 o;
    o.x = f2bf(v.x); o.y = f2bf(v.y); o.z = f2bf(v.z); o.w = f2bf(v.w);
    ((ushort4*)Wb)[i] = o;
    return;
  }
  const int row = blockIdx.x;
  const float4* xr = (const float4*)(x + (size_t)row * 2048);
  float4 a = xr[t];
  float4 b = xr[t + 256];
  float s = a.x + a.y + a.z + a.w + b.x + b.y + b.z + b.w;
  float q = a.x * a.x + a.y * a.y + a.z * a.z + a.w * a.w +
            b.x * b.x + b.y * b.y + b.z * b.z + b.w * b.w;
#pragma unroll
  for (int off = 32; off > 0; off >>= 1) {
    s += __shfl_down(s, off);
    q += __shfl_down(q, off);
  }
  __shared__ float red[8];
  const int w = t >> 6;
  if ((t & 63) == 0) { red[w] = s; red[4 + w] = q; }
  __syncthreads();
  s = red[0] + red[1] + red[2] + red[3];
  q = red[4] + red[5] + red[6] + red[7];
  const float mean = s * (1.0f / 2048.0f);
  const float var = fmaxf(q * (1.0f / 2048.0f) - mean * mean, 0.0f);
  const float scl = rsqrtf(var + 1e-5f);
  ushort4 o0, o1;
  o0.x = f2bf((a.x - mean) * scl);
  o0.y = f2bf((a.y - mean) * scl);
  o0.z = f2bf((a.z - mean) * scl);
  o0.w = f2bf((a.w - mean) * scl);
  o1.x = f2bf((b.x - mean) * scl);
  o1.y = f2bf((b.y - mean) * scl);
  o1.z = f2bf((b.z - mean) * scl);
  o1.w = f2bf((b.w - mean) * scl);
  ushort4* orow = (ushort4*)(xn + (size_t)row * 2048);
  orow[t] = o0;
  orow[t + 256] = o1;
}

// ---------------- 256x256 8-phase GEMM with read-prefetch interleave -------
// LDS: buf*65536 + {A0:0, A1:16K, B0:32K, B1:48K}. Regions 128 rows x 128B.
// Stage map (per iter): P1:A1->buf1(t1)  P2:B0->buf0(t2)  P3:A0->buf0(t2)
//   P4:B1->buf0(t2)  P5:A1->buf0(t2)  P6:B0->buf1(t3)  P7:A0->buf1(t3)
//   P8:B1->buf1(t3).  vmcnt(6) at P4/P8 (ledger: steady-state leaves the
//   last 3 stage-pairs outstanding).  Reads prefetched one phase early:
//   P1 head: bF1(buf0.B1); P2 interleave: aF<-buf0.A1; P4 tail(post-vmcnt):
//   aF<-buf1.A0 + bF0<-buf1.B0; P5 head: bF1(buf1.B1); P6 interleave:
//   aF<-buf1.A1; P8 tail(post-vmcnt): aF<-buf0.A0 + bF0<-buf0.B0.
//   All prefetch targets verified drained-before-issue and disjoint from
//   every stage issued before their consumption.

#define STG_A(buf, h, kt)                                              \
  do {                                                                 \
    const char* s_ = pA + (size_t)((h) * 128) * 4096 + (kt) * 128;     \
    char* d_ = lds + (buf) * 65536 + (h) * 16384 + tid * 16;           \
    async16(d_, s_);                                                   \
    async16(d_ + 8192, s_ + 64 * 4096);                                \
  } while (0)

#define STG_B(buf, h, kt)                                              \
  do {                                                                 \
    const char* s_ = pB + (size_t)((h) * 128) * 4096 + (kt) * 128;     \
    char* d_ = lds + 32768 + (buf) * 65536 + (h) * 16384 + tid * 16;   \
    async16(d_, s_);                                                   \
    async16(d_ + 8192, s_ + 64 * 4096);                                \
  } while (0)

#define LDA_S(buf, qm, S)                                              \
  do {                                                                 \
    _Pragma("unroll") for (int i_ = 0; i_ < 4; ++i_) {                 \
      const char* p_ = lds + (buf) * 65536 + (qm) * 16384 + abase + i_ * 2048; \
      aF[i_][S] = *(const b16x8*)(p_ + ((S) ? cs1 : cs0));             \
    }                                                                  \
  } while (0)

#define LDA(buf, qm) do { LDA_S(buf, qm, 0); LDA_S(buf, qm, 1); } while (0)

#define LDB(dstf, buf, qn)                                             \
  do {                                                                 \
    _Pragma("unroll") for (int j_ = 0; j_ < 2; ++j_) {                 \
      const char* p_ = lds + (buf) * 65536 + (qn) * 16384 + bbase + j_ * 2048; \
      dstf[j_][0] = *(const b16x8*)(p_ + cs0);                         \
      dstf[j_][1] = *(const b16x8*)(p_ + cs1);                         \
    }                                                                  \
  } while (0)

#define MFMA_H(qm, qn, BF, S)                                          \
  do {                                                                 \
    __builtin_amdgcn_s_setprio(1);                                     \
    _Pragma("unroll") for (int i_ = 0; i_ < 4; ++i_) {                 \
      _Pragma("unroll") for (int j_ = 0; j_ < 2; ++j_) {               \
        acc[(qm) * 4 + i_][(qn) * 2 + j_] =                            \
            __builtin_amdgcn_mfma_f32_16x16x32_bf16(                   \
                aF[i_][S], BF[j_][S], acc[(qm) * 4 + i_][(qn) * 2 + j_], 0, 0, 0); \
      }                                                                \
    }                                                                  \
    __builtin_amdgcn_s_setprio(0);                                     \
  } while (0)

#define MFMA_Q(qm, qn, BF)                                             \
  do { MFMA_H(qm, qn, BF, 0); MFMA_H(qm, qn, BF, 1); } while (0)

#define BARR                                                           \
  do {                                                                 \
    __builtin_amdgcn_s_barrier();                                      \
    asm volatile("" ::: "memory");                                     \
  } while (0)

#define LGKM0                                                          \
  do {                                                                 \
    asm volatile("s_waitcnt lgkmcnt(0)" ::: "memory");                 \
    __builtin_amdgcn_sched_barrier(0);                                 \
  } while (0)

#define SB0 __builtin_amdgcn_sched_barrier(0)
#define VMC(n) asm volatile("s_waitcnt vmcnt(" #n ")" ::: "memory")

__global__ __launch_bounds__(512, 2) void gemm8p(
    const unsigned short* __restrict__ A, const unsigned short* __restrict__ B,
    float* __restrict__ C) {
  __shared__ __align__(16) char lds[131072];

  const int bid0 = blockIdx.x;                       // 512 blocks
  const int bid = (bid0 & 7) * 64 + (bid0 >> 3);     // XCD swizzle (512%8==0)
  const int bm = bid >> 3;                           // 0..63
  const int bn = bid & 7;                            // 0..7

  const int tid = threadIdx.x;
  const int w = tid >> 6, l = tid & 63;
  const int wr = w >> 2, wc = w & 3;
  const int fr = l & 15, fg = l >> 4;

  // staging source (linear LDS dest, inverse-swizzled global source)
  const int arow = tid >> 3;
  const int swz = ((tid & 7) << 4) ^ ((arow & 7) << 4);
  const char* pA = (const char*)A + (size_t)(bm * 256 + arow) * 4096 + swz;
  const char* pB = (const char*)B + (size_t)(bn * 256 + arow) * 4096 + swz;

  // ds_read offsets (swizzled) — round-2 proven zero-conflict pattern
  const int cswz = (fg << 4) ^ ((fr & 7) << 4);
  const int cs0 = cswz, cs1 = cswz ^ 64;
  const int abase = (wr * 64 + fr) * 128;
  const int bbase = 32768 + (wc * 32 + fr) * 128;

  f32x4 acc[8][4] = {};
  b16x8 aF[4][2], bF0[2][2], bF1[2][2];

  // prologue: t0 full -> buf0; t1: B0,A0,B1 -> buf1
  STG_A(0, 0, 0); STG_B(0, 0, 0); STG_B(0, 1, 0); STG_A(0, 1, 0);
  STG_B(1, 0, 1); STG_A(1, 0, 1); STG_B(1, 1, 1);
  VMC(6);
  BARR;
  LDA(0, 0); LDB(bF0, 0, 0);   // P1@it0 operands

#pragma unroll 1
  for (int it = 0; it < 16; ++it) {
    const int t1 = 2 * it + 1, t2 = 2 * it + 2, t3 = 2 * it + 3;
    const bool s2 = (it < 15);

    // P1: Q(0,0) buf0. Prefetch P2's bF1 (buf0.B1: staged P4-prev, drained P8-prev).
    STG_A(1, 1, t1);
    BARR; LGKM0;
    LDB(bF1, 0, 1); SB0;
    MFMA_Q(0, 0, bF0);
    BARR;

    // P2: Q(0,1) buf0. Interleave: refill aF from buf0.A1 between halves.
    if (s2) STG_B(0, 0, t2);
    BARR; LGKM0;
    MFMA_H(0, 1, bF1, 0);
    SB0; LDA_S(0, 1, 0); SB0;     // new aF[*][0] (WAR after half-1)
    MFMA_H(0, 1, bF1, 1);
    SB0; LDA_S(0, 1, 1);          // new aF[*][1]
    BARR;

    // P3: Q(1,1) buf0 (aF = buf0.A1 from P2 interleave).
    if (s2) STG_A(0, 0, t2);
    BARR; LGKM0;
    MFMA_Q(1, 1, bF1);
    BARR;

    // P4: Q(1,0) buf0. After vmcnt: prefetch P5's aF/bF0 from buf1 (drained here).
    if (s2) STG_B(0, 1, t2);
    BARR;
    MFMA_Q(1, 0, bF0);
    if (s2) { VMC(6); } else { VMC(0); }
    SB0; LDA(1, 0); LDB(bF0, 1, 0);
    BARR;

    // P5: Q(0,0) buf1. Prefetch P6's bF1 (buf1.B1: staged P8-prev, drained P4-this).
    if (s2) STG_A(0, 1, t2);
    BARR; LGKM0;
    LDB(bF1, 1, 1); SB0;
    MFMA_Q(0, 0, bF0);
    BARR;

    // P6: Q(0,1) buf1. Interleave: refill aF from buf1.A1 (staged P1-this,
    // drained P4-this).
    if (s2) STG_B(1, 0, t3);
    BARR; LGKM0;
    MFMA_H(0, 1, bF1, 0);
    SB0; LDA_S(1, 1, 0); SB0;
    MFMA_H(0, 1, bF1, 1);
    SB0; LDA_S(1, 1, 1);
    BARR;

    // P7: Q(1,1) buf1.
    if (s2) STG_A(1, 0, t3);
    BARR; LGKM0;
    MFMA_Q(1, 1, bF1);
    BARR;

    // P8: Q(1,0) buf1. After vmcnt: prefetch next-P1's aF/bF0 from buf0
    // (A0/B0 staged P2/P3-this, drained here).
    if (s2) STG_B(1, 1, t3);
    BARR;
    MFMA_Q(1, 0, bF0);
    if (s2) { VMC(6); SB0; LDA(0, 0); LDB(bF0, 0, 0); }
    BARR;
  }

  // epilogue: sigmoid + store. C/D frag: row = fg*4 + r, col = fr.
  float* gC = C + (size_t)(bm * 256) * 2048 + bn * 256;
#pragma unroll
  for (int qm = 0; qm < 2; ++qm) {
#pragma unroll
    for (int i = 0; i < 4; ++i) {
#pragma unroll
      for (int qn = 0; qn < 2; ++qn) {
#pragma unroll
        for (int j = 0; j < 2; ++j) {
#pragma unroll
          for (int r = 0; r < 4; ++r) {
            const int row = qm * 128 + wr * 64 + i * 16 + fg * 4 + r;
            const int col = qn * 128 + wc * 32 + j * 16 + fr;
            const float y = acc[qm * 4 + i][qn * 2 + j][r];
            gC[(size_t)row * 2048 + col] =
                __builtin_amdgcn_rcpf(1.0f + __expf(-y));
          }
        }
      }
    }
  }
}

extern "C" void kernel_launch(void* const* d_in, const int* in_sizes, int n_in,
                              void* d_out, int out_size, void* d_ws, size_t ws_size,
                              hipStream_t stream) {
  const float* x = (const float*)d_in[0];
  const float* W = (const float*)d_in[1];
  float* out = (float*)d_out;

  unsigned short* xnb = (unsigned short*)d_ws;
  unsigned short* Wb =
      (unsigned short*)((char*)d_ws + (size_t)16384 * 2048 * 2);

  ln_wconv_kernel<<<16384 + 4096, 256, 0, stream>>>(x, xnb, W, Wb);
  gemm8p<<<512, 512, 0, stream>>>(xnb, Wb, out);
}

// Round 5
// 160.420 us; speedup vs baseline: 1.1242x; 1.0263x over previous
//
#include <hip/hip_runtime.h>
#include <hip/hip_bf16.h>
#include <stdint.h>

// LNLinearSigmoid: LayerNorm(x) @ W^T -> sigmoid
// Round 5: round-4 GEMM (256x256, 8-phase, 16x16x32 MFMA, zero-conflict XOR
// swizzle, vmcnt(6), read-prefetch interleave) with ONE barrier per phase
// (post-MFMA barrier removed; stage-vs-read safety ledger re-verified).
// ws >= 75.5 MB.

typedef __attribute__((ext_vector_type(4))) float f32x4;
typedef __attribute__((ext_vector_type(8))) __bf16 b16x8;

__device__ __forceinline__ void async16(void* lds_p, const void* g) {
  __builtin_amdgcn_global_load_lds(
      (const __attribute__((address_space(1))) void*)g,
      (__attribute__((address_space(3))) void*)lds_p, 16, 0, 0);
}

__device__ __forceinline__ unsigned short f2bf(float f) {
  uint32_t u = __float_as_uint(f);
  u += 0x7FFFu + ((u >> 16) & 1u);
  return (unsigned short)(u >> 16);
}

// ---------------- LN (blocks 0..16383) + W conv (blocks 16384..20479) ------
__global__ __launch_bounds__(256) void ln_wconv_kernel(
    const float* __restrict__ x, unsigned short* __restrict__ xn,
    const float* __restrict__ W, unsigned short* __restrict__ Wb) {
  const int t = threadIdx.x;
  if (blockIdx.x >= 16384) {
    const size_t i = (size_t)(blockIdx.x - 16384) * 256 + t;
    float4 v = ((const float4*)W)[i];
    ushort4 o;
    o.x = f2bf(v.x); o.y = f2bf(v.y); o.z = f2bf(v.z); o.w = f2bf(v.w);
    ((ushort4*)Wb)[i] = o;
    return;
  }
  const int row = blockIdx.x;
  const float4* xr = (const float4*)(x + (size_t)row * 2048);
  float4 a = xr[t];
  float4 b = xr[t + 256];
  float s = a.x + a.y + a.z + a.w + b.x + b.y + b.z + b.w;
  float q = a.x * a.x + a.y * a.y + a.z * a.z + a.w * a.w +
            b.x * b.x + b.y * b.y + b.z * b.z + b.w * b.w;
#pragma unroll
  for (int off = 32; off > 0; off >>= 1) {
    s += __shfl_down(s, off);
    q += __shfl_down(q, off);
  }
  __shared__ float red[8];
  const int w = t >> 6;
  if ((t & 63) == 0) { red[w] = s; red[4 + w] = q; }
  __syncthreads();
  s = red[0] + red[1] + red[2] + red[3];
  q = red[4] + red[5] + red[6] + red[7];
  const float mean = s * (1.0f / 2048.0f);
  const float var = fmaxf(q * (1.0f / 2048.0f) - mean * mean, 0.0f);
  const float scl = rsqrtf(var + 1e-5f);
  ushort4 o0, o1;
  o0.x = f2bf((a.x - mean) * scl);
  o0.y = f2bf((a.y - mean) * scl);
  o0.z = f2bf((a.z - mean) * scl);
  o0.w = f2bf((a.w - mean) * scl);
  o1.x = f2bf((b.x - mean) * scl);
  o1.y = f2bf((b.y - mean) * scl);
  o1.z = f2bf((b.z - mean) * scl);
  o1.w = f2bf((b.w - mean) * scl);
  ushort4* orow = (ushort4*)(xn + (size_t)row * 2048);
  orow[t] = o0;
  orow[t + 256] = o1;
}

// ---------------- 256x256 8-phase GEMM, 1 barrier/phase --------------------
// LDS: buf*65536 + {A0:0, A1:16K, B0:32K, B1:48K}. Regions 128 rows x 128B.
// Stage map: P1:A1->buf1(t1) P2:B0->buf0(t2) P3:A0->buf0(t2) P4:B1->buf0(t2)
//   P5:A1->buf0(t2) P6:B0->buf1(t3) P7:A0->buf1(t3) P8:B1->buf1(t3).
// vmcnt(6) at P4/P8. Reads prefetched one phase early inside MFMA clusters.
// Each phase: [stage] BARR LGKM0 [prefetch] MFMA  (no trailing barrier).

#define STG_A(buf, h, kt)                                              \
  do {                                                                 \
    const char* s_ = pA + (size_t)((h) * 128) * 4096 + (kt) * 128;     \
    char* d_ = lds + (buf) * 65536 + (h) * 16384 + tid * 16;           \
    async16(d_, s_);                                                   \
    async16(d_ + 8192, s_ + 64 * 4096);                                \
  } while (0)

#define STG_B(buf, h, kt)                                              \
  do {                                                                 \
    const char* s_ = pB + (size_t)((h) * 128) * 4096 + (kt) * 128;     \
    char* d_ = lds + 32768 + (buf) * 65536 + (h) * 16384 + tid * 16;   \
    async16(d_, s_);                                                   \
    async16(d_ + 8192, s_ + 64 * 4096);                                \
  } while (0)

#define LDA_S(buf, qm, S)                                              \
  do {                                                                 \
    _Pragma("unroll") for (int i_ = 0; i_ < 4; ++i_) {                 \
      const char* p_ = lds + (buf) * 65536 + (qm) * 16384 + abase + i_ * 2048; \
      aF[i_][S] = *(const b16x8*)(p_ + ((S) ? cs1 : cs0));             \
    }                                                                  \
  } while (0)

#define LDA(buf, qm) do { LDA_S(buf, qm, 0); LDA_S(buf, qm, 1); } while (0)

#define LDB(dstf, buf, qn)                                             \
  do {                                                                 \
    _Pragma("unroll") for (int j_ = 0; j_ < 2; ++j_) {                 \
      const char* p_ = lds + (buf) * 65536 + (qn) * 16384 + bbase + j_ * 2048; \
      dstf[j_][0] = *(const b16x8*)(p_ + cs0);                         \
      dstf[j_][1] = *(const b16x8*)(p_ + cs1);                         \
    }                                                                  \
  } while (0)

#define MFMA_H(qm, qn, BF, S)                                          \
  do {                                                                 \
    __builtin_amdgcn_s_setprio(1);                                     \
    _Pragma("unroll") for (int i_ = 0; i_ < 4; ++i_) {                 \
      _Pragma("unroll") for (int j_ = 0; j_ < 2; ++j_) {               \
        acc[(qm) * 4 + i_][(qn) * 2 + j_] =                            \
            __builtin_amdgcn_mfma_f32_16x16x32_bf16(                   \
                aF[i_][S], BF[j_][S], acc[(qm) * 4 + i_][(qn) * 2 + j_], 0, 0, 0); \
      }                                                                \
    }                                                                  \
    __builtin_amdgcn_s_setprio(0);                                     \
  } while (0)

#define MFMA_Q(qm, qn, BF)                                             \
  do { MFMA_H(qm, qn, BF, 0); MFMA_H(qm, qn, BF, 1); } while (0)

#define BARR                                                           \
  do {                                                                 \
    __builtin_amdgcn_s_barrier();                                      \
    asm volatile("" ::: "memory");                                     \
  } while (0)

#define LGKM0                                                          \
  do {                                                                 \
    asm volatile("s_waitcnt lgkmcnt(0)" ::: "memory");                 \
    __builtin_amdgcn_sched_barrier(0);                                 \
  } while (0)

#define SB0 __builtin_amdgcn_sched_barrier(0)
#define VMC(n) asm volatile("s_waitcnt vmcnt(" #n ")" ::: "memory")

__global__ __launch_bounds__(512, 2) void gemm8p(
    const unsigned short* __restrict__ A, const unsigned short* __restrict__ B,
    float* __restrict__ C) {
  __shared__ __align__(16) char lds[131072];

  const int bid0 = blockIdx.x;                       // 512 blocks
  const int bid = (bid0 & 7) * 64 + (bid0 >> 3);     // XCD swizzle (512%8==0)
  const int bm = bid >> 3;                           // 0..63
  const int bn = bid & 7;                            // 0..7

  const int tid = threadIdx.x;
  const int w = tid >> 6, l = tid & 63;
  const int wr = w >> 2, wc = w & 3;
  const int fr = l & 15, fg = l >> 4;

  // staging source (linear LDS dest, inverse-swizzled global source)
  const int arow = tid >> 3;
  const int swz = ((tid & 7) << 4) ^ ((arow & 7) << 4);
  const char* pA = (const char*)A + (size_t)(bm * 256 + arow) * 4096 + swz;
  const char* pB = (const char*)B + (size_t)(bn * 256 + arow) * 4096 + swz;

  // ds_read offsets (swizzled) — round-2 proven zero-conflict pattern
  const int cswz = (fg << 4) ^ ((fr & 7) << 4);
  const int cs0 = cswz, cs1 = cswz ^ 64;
  const int abase = (wr * 64 + fr) * 128;
  const int bbase = 32768 + (wc * 32 + fr) * 128;

  f32x4 acc[8][4] = {};
  b16x8 aF[4][2], bF0[2][2], bF1[2][2];

  // prologue: t0 full -> buf0; t1: B0,A0,B1 -> buf1
  STG_A(0, 0, 0); STG_B(0, 0, 0); STG_B(0, 1, 0); STG_A(0, 1, 0);
  STG_B(1, 0, 1); STG_A(1, 0, 1); STG_B(1, 1, 1);
  VMC(6);
  BARR;
  LDA(0, 0); LDB(bF0, 0, 0);   // P1@it0 operands

#pragma unroll 1
  for (int it = 0; it < 16; ++it) {
    const int t1 = 2 * it + 1, t2 = 2 * it + 2, t3 = 2 * it + 3;
    const bool s2 = (it < 15);

    // P1: Q(0,0) buf0. Prefetch P2's bF1 (buf0.B1: drained P8-prev VMC).
    STG_A(1, 1, t1);
    BARR; LGKM0;
    LDB(bF1, 0, 1); SB0;
    MFMA_Q(0, 0, bF0);

    // P2: Q(0,1) buf0. Interleave: refill aF from buf0.A1 (drained P8-prev).
    if (s2) STG_B(0, 0, t2);
    BARR; LGKM0;
    MFMA_H(0, 1, bF1, 0);
    SB0; LDA_S(0, 1, 0); SB0;
    MFMA_H(0, 1, bF1, 1);
    SB0; LDA_S(0, 1, 1);

    // P3: Q(1,1) buf0 (aF = buf0.A1 from P2 interleave).
    if (s2) STG_A(0, 0, t2);
    BARR; LGKM0;
    MFMA_Q(1, 1, bF1);

    // P4: Q(1,0) buf0. After vmcnt: prefetch P5's aF/bF0 from buf1.
    if (s2) STG_B(0, 1, t2);
    BARR;
    MFMA_Q(1, 0, bF0);
    if (s2) { VMC(6); } else { VMC(0); }
    SB0; LDA(1, 0); LDB(bF0, 1, 0);

    // P5: Q(0,0) buf1. Prefetch P6's bF1 (buf1.B1: drained P4-this VMC).
    if (s2) STG_A(0, 1, t2);
    BARR; LGKM0;
    LDB(bF1, 1, 1); SB0;
    MFMA_Q(0, 0, bF0);

    // P6: Q(0,1) buf1. Interleave: refill aF from buf1.A1 (drained P4-this).
    if (s2) STG_B(1, 0, t3);
    BARR; LGKM0;
    MFMA_H(0, 1, bF1, 0);
    SB0; LDA_S(1, 1, 0); SB0;
    MFMA_H(0, 1, bF1, 1);
    SB0; LDA_S(1, 1, 1);

    // P7: Q(1,1) buf1.
    if (s2) STG_A(1, 0, t3);
    BARR; LGKM0;
    MFMA_Q(1, 1, bF1);

    // P8: Q(1,0) buf1. After vmcnt: prefetch next-P1's aF/bF0 from buf0.
    if (s2) STG_B(1, 1, t3);
    BARR;
    MFMA_Q(1, 0, bF0);
    if (s2) { VMC(6); SB0; LDA(0, 0); LDB(bF0, 0, 0); }
  }

  // epilogue: sigmoid + store. C/D frag: row = fg*4 + r, col = fr.
  float* gC = C + (size_t)(bm * 256) * 2048 + bn * 256;
#pragma unroll
  for (int qm = 0; qm < 2; ++qm) {
#pragma unroll
    for (int i = 0; i < 4; ++i) {
#pragma unroll
      for (int qn = 0; qn < 2; ++qn) {
#pragma unroll
        for (int j = 0; j < 2; ++j) {
#pragma unroll
          for (int r = 0; r < 4; ++r) {
            const int row = qm * 128 + wr * 64 + i * 16 + fg * 4 + r;
            const int col = qn * 128 + wc * 32 + j * 16 + fr;
            const float y = acc[qm * 4 + i][qn * 2 + j][r];
            gC[(size_t)row * 2048 + col] =
                __builtin_amdgcn_rcpf(1.0f + __expf(-y));
          }
        }
      }
    }
  }
}

extern "C" void kernel_launch(void* const* d_in, const int* in_sizes, int n_in,
                              void* d_out, int out_size, void* d_ws, size_t ws_size,
                              hipStream_t stream) {
  const float* x = (const float*)d_in[0];
  const float* W = (const float*)d_in[1];
  float* out = (float*)d_out;

  unsigned short* xnb = (unsigned short*)d_ws;
  unsigned short* Wb =
      (unsigned short*)((char*)d_ws + (size_t)16384 * 2048 * 2);

  ln_wconv_kernel<<<16384 + 4096, 256, 0, stream>>>(x, xnb, W, Wb);
  gemm8p<<<512, 512, 0, stream>>>(xnb, Wb, out);
}

// Round 6
// 159.917 us; speedup vs baseline: 1.1278x; 1.0031x over previous
//
#include <hip/hip_runtime.h>
#include <hip/hip_bf16.h>
#include <stdint.h>

// LNLinearSigmoid: LayerNorm(x) @ W^T -> sigmoid
// Round 6: round-5 GEMM with phase pairs MERGED -> 4 barriers/iter.
// Each phase = 2 C-quadrants (32 MFMA) + 1 pre-barrier stage + 1 mid-cluster
// stage. vmcnt(6) ledger re-verified (drains exactly the buffer the next
// cluster reads). Reads prefetched one quadrant ahead inside MFMA clusters.
// ws >= 75.5 MB.

typedef __attribute__((ext_vector_type(4))) float f32x4;
typedef __attribute__((ext_vector_type(8))) __bf16 b16x8;

__device__ __forceinline__ void async16(void* lds_p, const void* g) {
  __builtin_amdgcn_global_load_lds(
      (const __attribute__((address_space(1))) void*)g,
      (__attribute__((address_space(3))) void*)lds_p, 16, 0, 0);
}

__device__ __forceinline__ unsigned short f2bf(float f) {
  uint32_t u = __float_as_uint(f);
  u += 0x7FFFu + ((u >> 16) & 1u);
  return (unsigned short)(u >> 16);
}

// ---------------- LN (blocks 0..16383) + W conv (blocks 16384..20479) ------
__global__ __launch_bounds__(256) void ln_wconv_kernel(
    const float* __restrict__ x, unsigned short* __restrict__ xn,
    const float* __restrict__ W, unsigned short* __restrict__ Wb) {
  const int t = threadIdx.x;
  if (blockIdx.x >= 16384) {
    const size_t i = (size_t)(blockIdx.x - 16384) * 256 + t;
    float4 v = ((const float4*)W)[i];
    ushort4 o;
    o.x = f2bf(v.x); o.y = f2bf(v.y); o.z = f2bf(v.z); o.w = f2bf(v.w);
    ((ushort4*)Wb)[i] = o;
    return;
  }
  const int row = blockIdx.x;
  const float4* xr = (const float4*)(x + (size_t)row * 2048);
  float4 a = xr[t];
  float4 b = xr[t + 256];
  float s = a.x + a.y + a.z + a.w + b.x + b.y + b.z + b.w;
  float q = a.x * a.x + a.y * a.y + a.z * a.z + a.w * a.w +
            b.x * b.x + b.y * b.y + b.z * b.z + b.w * b.w;
#pragma unroll
  for (int off = 32; off > 0; off >>= 1) {
    s += __shfl_down(s, off);
    q += __shfl_down(q, off);
  }
  __shared__ float red[8];
  const int w = t >> 6;
  if ((t & 63) == 0) { red[w] = s; red[4 + w] = q; }
  __syncthreads();
  s = red[0] + red[1] + red[2] + red[3];
  q = red[4] + red[5] + red[6] + red[7];
  const float mean = s * (1.0f / 2048.0f);
  const float var = fmaxf(q * (1.0f / 2048.0f) - mean * mean, 0.0f);
  const float scl = rsqrtf(var + 1e-5f);
  ushort4 o0, o1;
  o0.x = f2bf((a.x - mean) * scl);
  o0.y = f2bf((a.y - mean) * scl);
  o0.z = f2bf((a.z - mean) * scl);
  o0.w = f2bf((a.w - mean) * scl);
  o1.x = f2bf((b.x - mean) * scl);
  o1.y = f2bf((b.y - mean) * scl);
  o1.z = f2bf((b.z - mean) * scl);
  o1.w = f2bf((b.w - mean) * scl);
  ushort4* orow = (ushort4*)(xn + (size_t)row * 2048);
  orow[t] = o0;
  orow[t + 256] = o1;
}

// ---------------- 256x256 GEMM, 4 merged phases, 4 barriers/iter -----------
// LDS: buf*65536 + {A0:0, A1:16K, B0:32K, B1:48K}. Regions 128 rows x 128B.
// M1: Q(0,0)+Q(0,1) buf0. pre:STG A1->buf1(t1). mid:STG B0->buf0(t2).
//     head-prefetch bF1<-buf0.B1; aF refill <-buf0.A1 interleaved in Q(0,1).
// M2: Q(1,1)+Q(1,0) buf0. pre:STG A0->buf0(t2). mid:STG B1->buf0(t2).
//     tail: VMC(6) then prefetch aF<-buf1.A0, bF0<-buf1.B0.
// M3: Q(0,0)+Q(0,1) buf1. pre:STG A1->buf0(t2). mid:STG B0->buf1(t3).
//     head-prefetch bF1<-buf1.B1; aF refill <-buf1.A1.
// M4: Q(1,1)+Q(1,0) buf1. pre:STG A0->buf1(t3). mid:STG B1->buf1(t3).
//     tail: VMC(6) then prefetch aF<-buf0.A0, bF0<-buf0.B0.
// Ledger: M2-VMC(6) drains {B0',A0',B1',A1'}(t-odd, buf1) leaving t2's 6;
//         M4-VMC(6) drains {B0,A0,B1,A1}(t2, buf0) leaving t3's 6. Each
//         stage issues >=600cy (16 MFMA) after its region's reads drained.

#define STG_A(buf, h, kt)                                              \
  do {                                                                 \
    const char* s_ = pA + (size_t)((h) * 128) * 4096 + (kt) * 128;     \
    char* d_ = lds + (buf) * 65536 + (h) * 16384 + tid * 16;           \
    async16(d_, s_);                                                   \
    async16(d_ + 8192, s_ + 64 * 4096);                                \
  } while (0)

#define STG_B(buf, h, kt)                                              \
  do {                                                                 \
    const char* s_ = pB + (size_t)((h) * 128) * 4096 + (kt) * 128;     \
    char* d_ = lds + 32768 + (buf) * 65536 + (h) * 16384 + tid * 16;   \
    async16(d_, s_);                                                   \
    async16(d_ + 8192, s_ + 64 * 4096);                                \
  } while (0)

#define LDA_S(buf, qm, S)                                              \
  do {                                                                 \
    _Pragma("unroll") for (int i_ = 0; i_ < 4; ++i_) {                 \
      const char* p_ = lds + (buf) * 65536 + (qm) * 16384 + abase + i_ * 2048; \
      aF[i_][S] = *(const b16x8*)(p_ + ((S) ? cs1 : cs0));             \
    }                                                                  \
  } while (0)

#define LDA(buf, qm) do { LDA_S(buf, qm, 0); LDA_S(buf, qm, 1); } while (0)

#define LDB(dstf, buf, qn)                                             \
  do {                                                                 \
    _Pragma("unroll") for (int j_ = 0; j_ < 2; ++j_) {                 \
      const char* p_ = lds + (buf) * 65536 + (qn) * 16384 + bbase + j_ * 2048; \
      dstf[j_][0] = *(const b16x8*)(p_ + cs0);                         \
      dstf[j_][1] = *(const b16x8*)(p_ + cs1);                         \
    }                                                                  \
  } while (0)

#define MFMA_H(qm, qn, BF, S)                                          \
  do {                                                                 \
    __builtin_amdgcn_s_setprio(1);                                     \
    _Pragma("unroll") for (int i_ = 0; i_ < 4; ++i_) {                 \
      _Pragma("unroll") for (int j_ = 0; j_ < 2; ++j_) {               \
        acc[(qm) * 4 + i_][(qn) * 2 + j_] =                            \
            __builtin_amdgcn_mfma_f32_16x16x32_bf16(                   \
                aF[i_][S], BF[j_][S], acc[(qm) * 4 + i_][(qn) * 2 + j_], 0, 0, 0); \
      }                                                                \
    }                                                                  \
    __builtin_amdgcn_s_setprio(0);                                     \
  } while (0)

#define MFMA_Q(qm, qn, BF)                                             \
  do { MFMA_H(qm, qn, BF, 0); MFMA_H(qm, qn, BF, 1); } while (0)

#define BARR                                                           \
  do {                                                                 \
    __builtin_amdgcn_s_barrier();                                      \
    asm volatile("" ::: "memory");                                     \
  } while (0)

#define LGKM0                                                          \
  do {                                                                 \
    asm volatile("s_waitcnt lgkmcnt(0)" ::: "memory");                 \
    __builtin_amdgcn_sched_barrier(0);                                 \
  } while (0)

#define SB0 __builtin_amdgcn_sched_barrier(0)
#define VMC(n) asm volatile("s_waitcnt vmcnt(" #n ")" ::: "memory")

__global__ __launch_bounds__(512, 2) void gemm8p(
    const unsigned short* __restrict__ A, const unsigned short* __restrict__ B,
    float* __restrict__ C) {
  __shared__ __align__(16) char lds[131072];

  const int bid0 = blockIdx.x;                       // 512 blocks
  const int bid = (bid0 & 7) * 64 + (bid0 >> 3);     // XCD swizzle (512%8==0)
  const int bm = bid >> 3;                           // 0..63
  const int bn = bid & 7;                            // 0..7

  const int tid = threadIdx.x;
  const int w = tid >> 6, l = tid & 63;
  const int wr = w >> 2, wc = w & 3;
  const int fr = l & 15, fg = l >> 4;

  // staging source (linear LDS dest, inverse-swizzled global source)
  const int arow = tid >> 3;
  const int swz = ((tid & 7) << 4) ^ ((arow & 7) << 4);
  const char* pA = (const char*)A + (size_t)(bm * 256 + arow) * 4096 + swz;
  const char* pB = (const char*)B + (size_t)(bn * 256 + arow) * 4096 + swz;

  // ds_read offsets (swizzled) — proven zero-conflict pattern
  const int cswz = (fg << 4) ^ ((fr & 7) << 4);
  const int cs0 = cswz, cs1 = cswz ^ 64;
  const int abase = (wr * 64 + fr) * 128;
  const int bbase = 32768 + (wc * 32 + fr) * 128;

  f32x4 acc[8][4] = {};
  b16x8 aF[4][2], bF0[2][2], bF1[2][2];

  // prologue: t0 full -> buf0; t1: B0,A0,B1 -> buf1
  STG_A(0, 0, 0); STG_B(0, 0, 0); STG_B(0, 1, 0); STG_A(0, 1, 0);
  STG_B(1, 0, 1); STG_A(1, 0, 1); STG_B(1, 1, 1);
  VMC(6);
  BARR;
  LDA(0, 0); LDB(bF0, 0, 0);   // M1@it0 operands

#pragma unroll 1
  for (int it = 0; it < 16; ++it) {
    const int t1 = 2 * it + 1, t2 = 2 * it + 2, t3 = 2 * it + 3;
    const bool s2 = (it < 15);

    // M1: Q(0,0)+Q(0,1) on buf0.
    STG_A(1, 1, t1);                 // pre: buf1.A1 <- t1
    BARR; LGKM0;
    LDB(bF1, 0, 1); SB0;             // prefetch buf0.B1 (drained prev M4-VMC)
    MFMA_Q(0, 0, bF0);
    if (s2) STG_B(0, 0, t2);         // mid: buf0.B0 (reads drained M1 head)
    SB0;
    MFMA_H(0, 1, bF1, 0);
    SB0; LDA_S(0, 1, 0); SB0;        // refill aF[.][0] <- buf0.A1
    MFMA_H(0, 1, bF1, 1);
    SB0; LDA_S(0, 1, 1);             // refill aF[.][1]

    // M2: Q(1,1)+Q(1,0) on buf0.
    if (s2) STG_A(0, 0, t2);         // pre: buf0.A0 (drained M1 head, +cluster)
    BARR; LGKM0;
    MFMA_Q(1, 1, bF1);
    if (s2) STG_B(0, 1, t2);         // mid: buf0.B1 (reads drained M2 head)
    SB0;
    MFMA_Q(1, 0, bF0);
    if (s2) { VMC(6); } else { VMC(0); }
    SB0; LDA(1, 0); LDB(bF0, 1, 0);  // prefetch buf1.A0/B0 (just drained)

    // M3: Q(0,0)+Q(0,1) on buf1.
    if (s2) STG_A(0, 1, t2);         // pre: buf0.A1 (refill reads drained M2 head)
    BARR; LGKM0;
    LDB(bF1, 1, 1); SB0;             // prefetch buf1.B1 (drained M2-VMC)
    MFMA_Q(0, 0, bF0);
    if (s2) STG_B(1, 0, t3);         // mid: buf1.B0 (reads drained M3 head)
    SB0;
    MFMA_H(0, 1, bF1, 0);
    SB0; LDA_S(1, 1, 0); SB0;        // refill aF <- buf1.A1 (landed: M2-VMC)
    MFMA_H(0, 1, bF1, 1);
    SB0; LDA_S(1, 1, 1);

    // M4: Q(1,1)+Q(1,0) on buf1.
    if (s2) STG_A(1, 0, t3);         // pre: buf1.A0 (drained M3 head)
    BARR; LGKM0;
    MFMA_Q(1, 1, bF1);
    if (s2) STG_B(1, 1, t3);         // mid: buf1.B1 (reads drained M4 head)
    SB0;
    MFMA_Q(1, 0, bF0);
    if (s2) { VMC(6); SB0; LDA(0, 0); LDB(bF0, 0, 0); }  // prefetch buf0(t2)
  }

  // epilogue: sigmoid + store. C/D frag: row = fg*4 + r, col = fr.
  float* gC = C + (size_t)(bm * 256) * 2048 + bn * 256;
#pragma unroll
  for (int qm = 0; qm < 2; ++qm) {
#pragma unroll
    for (int i = 0; i < 4; ++i) {
#pragma unroll
      for (int qn = 0; qn < 2; ++qn) {
#pragma unroll
        for (int j = 0; j < 2; ++j) {
#pragma unroll
          for (int r = 0; r < 4; ++r) {
            const int row = qm * 128 + wr * 64 + i * 16 + fg * 4 + r;
            const int col = qn * 128 + wc * 32 + j * 16 + fr;
            const float y = acc[qm * 4 + i][qn * 2 + j][r];
            gC[(size_t)row * 2048 + col] =
                __builtin_amdgcn_rcpf(1.0f + __expf(-y));
          }
        }
      }
    }
  }
}

extern "C" void kernel_launch(void* const* d_in, const int* in_sizes, int n_in,
                              void* d_out, int out_size, void* d_ws, size_t ws_size,
                              hipStream_t stream) {
  const float* x = (const float*)d_in[0];
  const float* W = (const float*)d_in[1];
  float* out = (float*)d_out;

  unsigned short* xnb = (unsigned short*)d_ws;
  unsigned short* Wb =
      (unsigned short*)((char*)d_ws + (size_t)16384 * 2048 * 2);

  ln_wconv_kernel<<<16384 + 4096, 256, 0, stream>>>(x, xnb, W, Wb);
  gemm8p<<<512, 512, 0, stream>>>(xnb, Wb, out);
}